// Round 1
// baseline (225.784 us; speedup 1.0000x reference)
//
#include <hip/hip_runtime.h>
#include <stdint.h>
#include <math.h>

#define B_ 2
#define S_ 2048
#define D_ 1024
#define H_ 16
#define HD_ 64
#define QBLK 64
#define KVBLK 64

typedef __bf16 bf16_t;
typedef __bf16 bf16x4 __attribute__((ext_vector_type(4)));
typedef __bf16 bf16x8 __attribute__((ext_vector_type(8)));
typedef float f32x4 __attribute__((ext_vector_type(4)));
typedef float float4v __attribute__((ext_vector_type(4)));

#define L2E 1.4426950408889634f

__device__ __forceinline__ void gload_lds16(const bf16_t* g, bf16_t* l) {
  __builtin_amdgcn_global_load_lds((const __attribute__((address_space(1))) void*)g,
                                   (__attribute__((address_space(3))) void*)l, 16, 0, 0);
}

// ---------------- cast f32 -> bf16 (vector x4) ----------------
__global__ void cast_bf16_kernel(const float* __restrict__ src, bf16_t* __restrict__ dst, int n4) {
  int i = blockIdx.x * blockDim.x + threadIdx.x;
  int stride = gridDim.x * blockDim.x;
  for (; i < n4; i += stride) {
    float4v f = *(const float4v*)(src + (size_t)i * 4);
    bf16x4 o;
    o[0] = (__bf16)f[0]; o[1] = (__bf16)f[1]; o[2] = (__bf16)f[2]; o[3] = (__bf16)f[3];
    *(bf16x4*)(dst + (size_t)i * 4) = o;
  }
}

// ---------------- GEMM: C[m][n] = sum_k A[m][k] * B[n][k] ----------------
// A: [M][K] bf16 row-major, B: [N][K] bf16 row-major (i.e. B-transposed layout).
// 128x128 tile, BK=32, 256 threads (2x2 waves), 16x16x32 MFMA. m97 structure.
template <typename OutT>
__global__ __launch_bounds__(256) void gemm_bt(const bf16_t* __restrict__ A,
                                               const bf16_t* __restrict__ Bm,
                                               OutT* __restrict__ C,
                                               int M, int N, int K) {
  __shared__ bf16_t As[128 * 32];
  __shared__ bf16_t Bs[128 * 32];
  const int t = threadIdx.x;
  const int lane = t & 63, wave = t >> 6;
  const int wr = wave >> 1, wc = wave & 1;
  const int qr = lane & 15, g = lane >> 4;
  const int bm = blockIdx.x, bn = blockIdx.y;

  f32x4 acc[4][4];
#pragma unroll
  for (int m = 0; m < 4; m++)
#pragma unroll
    for (int n = 0; n < 4; n++) acc[m][n] = (f32x4){0.f, 0.f, 0.f, 0.f};

  const bf16_t* Abase = A + (size_t)(bm * 128) * K;
  const bf16_t* Bbase = Bm + (size_t)(bn * 128) * K;
  const int srow = t >> 2;            // row within 64-row half
  const int scol = (t & 3) * 8;       // k-elems offset within 32-elem (64B) row chunk

  for (int kk = 0; kk < K; kk += 32) {
    gload_lds16(Abase + (size_t)srow * K + kk + scol,        As + t * 8);
    gload_lds16(Abase + (size_t)(srow + 64) * K + kk + scol, As + 2048 + t * 8);
    gload_lds16(Bbase + (size_t)srow * K + kk + scol,        Bs + t * 8);
    gload_lds16(Bbase + (size_t)(srow + 64) * K + kk + scol, Bs + 2048 + t * 8);
    __syncthreads();
    bf16x8 a[4], b[4];
#pragma unroll
    for (int m = 0; m < 4; m++)
      a[m] = *(const bf16x8*)(As + (wr * 64 + m * 16 + qr) * 32 + g * 8);
#pragma unroll
    for (int n = 0; n < 4; n++)
      b[n] = *(const bf16x8*)(Bs + (wc * 64 + n * 16 + qr) * 32 + g * 8);
#pragma unroll
    for (int m = 0; m < 4; m++)
#pragma unroll
      for (int n = 0; n < 4; n++)
        acc[m][n] = __builtin_amdgcn_mfma_f32_16x16x32_bf16(a[m], b[n], acc[m][n], 0, 0, 0);
    __syncthreads();
  }

#pragma unroll
  for (int m = 0; m < 4; m++) {
    int row0 = bm * 128 + wr * 64 + m * 16 + g * 4;
#pragma unroll
    for (int n = 0; n < 4; n++) {
      int col = bn * 128 + wc * 64 + n * 16 + qr;
#pragma unroll
      for (int r = 0; r < 4; r++)
        C[(size_t)(row0 + r) * N + col] = (OutT)acc[m][n][r];
    }
  }
}

// ---------------- RoPE on q,k + q-scale; writes Q,K as [B][H][S][HD] bf16 ----------------
__global__ void rope_qk_kernel(const bf16_t* __restrict__ qkv, const int* __restrict__ pos,
                               bf16_t* __restrict__ Q, bf16_t* __restrict__ Ko) {
  int idx = blockIdx.x * blockDim.x + threadIdx.x;
  if (idx >= B_ * S_ * H_ * 32) return;
  int i = idx & 31;
  int h = (idx >> 5) & (H_ - 1);
  int bs = idx >> 9;  // b*S + s
  const bf16_t* row = qkv + (size_t)bs * (3 * D_) + h * 192;
  float q1 = (float)row[i], q2 = (float)row[i + 32];
  float k1 = (float)row[64 + i], k2 = (float)row[96 + i];
  int p = pos[bs];
  // inv_freq = 10000^(-i/32) = exp2(-i/32 * log2(10000))
  float inv = exp2f(-(float)i * (13.287712379549449f / 32.0f));
  float ang = (float)p * inv;
  float sn, cs;
  sincosf(ang, &sn, &cs);
  float qo1 = (q1 * cs - q2 * sn) * 0.125f;
  float qo2 = (q2 * cs + q1 * sn) * 0.125f;
  float ko1 = k1 * cs - k2 * sn;
  float ko2 = k2 * cs + k1 * sn;
  int b = bs >> 11, s = bs & (S_ - 1);
  size_t o = ((size_t)(b * H_ + h) * S_ + s) * HD_ + i;
  Q[o] = (__bf16)qo1;  Q[o + 32] = (__bf16)qo2;
  Ko[o] = (__bf16)ko1; Ko[o + 32] = (__bf16)ko2;
}

// ---------------- V transpose: qkv v-slice -> Vt [B][H][HD][S] bf16 ----------------
__global__ __launch_bounds__(256) void v_transpose_kernel(const bf16_t* __restrict__ qkv,
                                                          bf16_t* __restrict__ Vt) {
  __shared__ bf16_t tile[64][72];
  int t = threadIdx.x;
  int s0 = blockIdx.x * 64;
  int h = blockIdx.y, b = blockIdx.z;
  int sl = t >> 4;            // 0..15
  int cb = (t & 15) * 4;      // d col base
#pragma unroll
  for (int it = 0; it < 4; it++) {
    int s = sl + it * 16;
    const bf16_t* src = qkv + (size_t)(b * S_ + s0 + s) * (3 * D_) + h * 192 + 128 + cb;
    bf16x4 v = *(const bf16x4*)src;
    tile[cb + 0][s] = v[0]; tile[cb + 1][s] = v[1];
    tile[cb + 2][s] = v[2]; tile[cb + 3][s] = v[3];
  }
  __syncthreads();
#pragma unroll
  for (int it = 0; it < 4; it++) {
    int d = sl + it * 16;
    bf16x4 v;
    v[0] = tile[d][cb]; v[1] = tile[d][cb + 1]; v[2] = tile[d][cb + 2]; v[3] = tile[d][cb + 3];
    *(bf16x4*)(Vt + ((size_t)((b * H_ + h) * HD_ + d)) * S_ + s0 + cb) = v;
  }
}

// ---------------- flash attention (causal via positions) ----------------
// grid: (S/QBLK, H, B), 256 threads = 4 waves; wave wv owns q rows [q0+wv*16, +16)
__global__ __launch_bounds__(256) void attn_kernel(const bf16_t* __restrict__ Q,
                                                   const bf16_t* __restrict__ K,
                                                   const bf16_t* __restrict__ Vt,
                                                   const int* __restrict__ pos,
                                                   bf16_t* __restrict__ O) {
  __shared__ bf16_t Ks[KVBLK * 64];   // [k_row][d], 16B-block XOR-swizzled
  __shared__ bf16_t Vs[64 * KVBLK];   // [d_row][s], 16B-block XOR-swizzled
  __shared__ bf16_t Ps[4][16 * 64];   // per-wave P, [q_row][k], swizzled

  const int t = threadIdx.x;
  const int lane = t & 63, wv = t >> 6;
  const int qr = lane & 15, g = lane >> 4;
  const int bx = blockIdx.x, h = blockIdx.y, b = blockIdx.z;
  const int q0 = bx * QBLK;

  const size_t bh = (size_t)(b * H_ + h);
  const bf16_t* Qb = Q + bh * (S_ * HD_);
  const bf16_t* Kb = K + bh * (S_ * HD_);
  const bf16_t* Vb = Vt + bh * (HD_ * S_);

  bf16x8 qf[2];
#pragma unroll
  for (int c = 0; c < 2; c++)
    qf[c] = *(const bf16x8*)(Qb + (size_t)(q0 + wv * 16 + qr) * HD_ + g * 8 + c * 32);

  int prow[4];
#pragma unroll
  for (int r = 0; r < 4; r++) prow[r] = pos[b * S_ + q0 + wv * 16 + 4 * g + r];

  // block-wide max position -> tile loop bound (same value in all waves)
  int myp = pos[b * S_ + q0 + lane];
#pragma unroll
  for (int off = 32; off > 0; off >>= 1) myp = max(myp, __shfl_xor(myp, off));
  const int ntiles = min(S_ / KVBLK, (myp >> 6) + 1);

  float m_run[4], l_run[4];
  f32x4 oacc[4];
#pragma unroll
  for (int r = 0; r < 4; r++) { m_run[r] = -__builtin_inff(); l_run[r] = 0.f; }
#pragma unroll
  for (int dt = 0; dt < 4; dt++) oacc[dt] = (f32x4){0.f, 0.f, 0.f, 0.f};

  for (int kt = 0; kt < ntiles; ++kt) {
    const int k0 = kt * KVBLK;
    __syncthreads();  // previous tile's LDS reads done before overwrite
    {
      int e0 = t, r0 = e0 >> 3, b0 = e0 & 7;
      int e1 = 256 + t, r1 = e1 >> 3, b1 = e1 & 7;
      gload_lds16(Kb + (size_t)(k0 + r0) * HD_ + ((b0 ^ (r0 & 7)) * 8), (bf16_t*)Ks + e0 * 8);
      gload_lds16(Kb + (size_t)(k0 + r1) * HD_ + ((b1 ^ (r1 & 7)) * 8), (bf16_t*)Ks + e1 * 8);
      gload_lds16(Vb + (size_t)r0 * S_ + k0 + ((b0 ^ (r0 & 7)) * 8), (bf16_t*)Vs + e0 * 8);
      gload_lds16(Vb + (size_t)r1 * S_ + k0 + ((b1 ^ (r1 & 7)) * 8), (bf16_t*)Vs + e1 * 8);
    }
    __syncthreads();

    // QK^T: 16 q x 64 k per wave
    f32x4 sc[4];
#pragma unroll
    for (int st = 0; st < 4; st++) {
      f32x4 a = (f32x4){0.f, 0.f, 0.f, 0.f};
#pragma unroll
      for (int c = 0; c < 2; c++) {
        int rowl = st * 16 + qr;
        bf16x8 kf = *(const bf16x8*)(Ks + rowl * 64 + (((g + 4 * c) ^ (rowl & 7)) * 8));
        a = __builtin_amdgcn_mfma_f32_16x16x32_bf16(qf[c], kf, a, 0, 0, 0);
      }
      sc[st] = a;
    }

    // online softmax (row q = 4*g + r; k = k0 + st*16 + qr across lanes)
#pragma unroll
    for (int r = 0; r < 4; r++) {
      float pv[4];
      float tm = -__builtin_inff();
#pragma unroll
      for (int st = 0; st < 4; st++) {
        int kglob = k0 + st * 16 + qr;
        float s = sc[st][r];
        pv[st] = (kglob <= prow[r]) ? s : -__builtin_inff();
        tm = fmaxf(tm, pv[st]);
      }
#pragma unroll
      for (int off = 1; off < 16; off <<= 1) tm = fmaxf(tm, __shfl_xor(tm, off));
      float mn = fmaxf(m_run[r], tm);
      float scale = (m_run[r] == -__builtin_inff()) ? 0.f : exp2f((m_run[r] - mn) * L2E);
      float rs = 0.f;
#pragma unroll
      for (int st = 0; st < 4; st++) {
        float p = (pv[st] == -__builtin_inff()) ? 0.f : exp2f((pv[st] - mn) * L2E);
        pv[st] = p;
        rs += p;
      }
#pragma unroll
      for (int off = 1; off < 16; off <<= 1) rs += __shfl_xor(rs, off);
      l_run[r] = l_run[r] * scale + rs;
      m_run[r] = mn;
#pragma unroll
      for (int dt = 0; dt < 4; dt++) oacc[dt][r] *= scale;
      int ql = 4 * g + r;
#pragma unroll
      for (int st = 0; st < 4; st++) {
        int k = st * 16 + qr;
        int blk = k >> 3;
        Ps[wv][ql * 64 + ((blk ^ (ql & 7)) * 8) + (k & 7)] = (__bf16)pv[st];
      }
    }

    // PV: oacc[dt] += P(16x64) * V(64x16dt)
#pragma unroll
    for (int c = 0; c < 2; c++) {
      bf16x8 pf = *(const bf16x8*)(&Ps[wv][0] + qr * 64 + (((g + 4 * c) ^ (qr & 7)) * 8));
#pragma unroll
      for (int dt = 0; dt < 4; dt++) {
        int rowv = dt * 16 + qr;
        bf16x8 vf = *(const bf16x8*)(Vs + rowv * 64 + (((g + 4 * c) ^ (rowv & 7)) * 8));
        oacc[dt] = __builtin_amdgcn_mfma_f32_16x16x32_bf16(pf, vf, oacc[dt], 0, 0, 0);
      }
    }
  }

#pragma unroll
  for (int r = 0; r < 4; r++) {
    float rl = (l_run[r] > 0.f) ? 1.0f / l_run[r] : 0.f;
    size_t orow = (size_t)(b * S_ + q0 + wv * 16 + 4 * g + r) * D_ + h * HD_;
#pragma unroll
    for (int dt = 0; dt < 4; dt++)
      O[orow + dt * 16 + qr] = (__bf16)(oacc[dt][r] * rl);
  }
}

extern "C" void kernel_launch(void* const* d_in, const int* in_sizes, int n_in,
                              void* d_out, int out_size, void* d_ws, size_t ws_size,
                              hipStream_t stream) {
  const float* inputs = (const float*)d_in[0];
  const int* positions = (const int*)d_in[1];
  const float* W_in = (const float*)d_in[2];
  const float* W_out = (const float*)d_in[3];
  float* out = (float*)d_out;

  bf16_t* X_bf = (bf16_t*)d_ws;                       // 4096*1024
  bf16_t* Win_bf = X_bf + (size_t)4096 * 1024;        // 3072*1024
  bf16_t* Wout_bf = Win_bf + (size_t)3072 * 1024;     // 1024*1024
  bf16_t* qkv_bf = Wout_bf + (size_t)1024 * 1024;     // 4096*3072
  bf16_t* Qb = qkv_bf + (size_t)4096 * 3072;          // B*H*S*HD
  bf16_t* Kb = Qb + (size_t)B_ * H_ * S_ * HD_;
  bf16_t* Vtb = Kb + (size_t)B_ * H_ * S_ * HD_;
  bf16_t* Ob = Vtb + (size_t)B_ * H_ * S_ * HD_;

  cast_bf16_kernel<<<dim3(2048), dim3(256), 0, stream>>>(inputs, X_bf, (4096 * 1024) / 4);
  cast_bf16_kernel<<<dim3(2048), dim3(256), 0, stream>>>(W_in, Win_bf, (3072 * 1024) / 4);
  cast_bf16_kernel<<<dim3(1024), dim3(256), 0, stream>>>(W_out, Wout_bf, (1024 * 1024) / 4);

  gemm_bt<bf16_t><<<dim3(32, 24), dim3(256), 0, stream>>>(X_bf, Win_bf, qkv_bf, 4096, 3072, 1024);

  rope_qk_kernel<<<dim3((B_ * S_ * H_ * 32) / 256), dim3(256), 0, stream>>>(qkv_bf, positions, Qb, Kb);
  v_transpose_kernel<<<dim3(S_ / 64, H_, B_), dim3(256), 0, stream>>>(qkv_bf, Vtb);

  attn_kernel<<<dim3(S_ / QBLK, H_, B_), dim3(256), 0, stream>>>(Qb, Kb, Vtb, positions, Ob);

  gemm_bt<float><<<dim3(32, 8), dim3(256), 0, stream>>>(Ob, Wout_bf, out, 4096, 1024, 1024);
}

// Round 2
// 182.412 us; speedup vs baseline: 1.2378x; 1.2378x over previous
//
#include <hip/hip_runtime.h>
#include <stdint.h>
#include <math.h>

#define B_ 2
#define S_ 2048
#define D_ 1024
#define H_ 16
#define HD_ 64
#define KVBLK 64

typedef __bf16 bf16_t;
typedef __bf16 bf16x4 __attribute__((ext_vector_type(4)));
typedef __bf16 bf16x8 __attribute__((ext_vector_type(8)));
typedef float f32x4 __attribute__((ext_vector_type(4)));
typedef float f32x16 __attribute__((ext_vector_type(16)));
typedef float float4v __attribute__((ext_vector_type(4)));

#define L2E 1.4426950408889634f
#define NINF (-__builtin_inff())

__device__ __forceinline__ void gload_lds16(const bf16_t* g, bf16_t* l) {
  __builtin_amdgcn_global_load_lds((const __attribute__((address_space(1))) void*)g,
                                   (__attribute__((address_space(3))) void*)l, 16, 0, 0);
}

__device__ __forceinline__ uint32_t packbf(float a, float b) {
  union { __bf16 h[2]; uint32_t u; } cvt;
  cvt.h[0] = (__bf16)a; cvt.h[1] = (__bf16)b;
  return cvt.u;
}

// ---------------- cast f32 -> bf16 (vector x4) ----------------
__global__ void cast_bf16_kernel(const float* __restrict__ src, bf16_t* __restrict__ dst, int n4) {
  int i = blockIdx.x * blockDim.x + threadIdx.x;
  int stride = gridDim.x * blockDim.x;
  for (; i < n4; i += stride) {
    float4v f = *(const float4v*)(src + (size_t)i * 4);
    bf16x4 o;
    o[0] = (__bf16)f[0]; o[1] = (__bf16)f[1]; o[2] = (__bf16)f[2]; o[3] = (__bf16)f[3];
    *(bf16x4*)(dst + (size_t)i * 4) = o;
  }
}

// ---------------- GEMM: C[m][n] = sum_k A[m][k] * B[n][k] ----------------
template <typename OutT>
__global__ __launch_bounds__(256) void gemm_bt(const bf16_t* __restrict__ A,
                                               const bf16_t* __restrict__ Bm,
                                               OutT* __restrict__ C,
                                               int M, int N, int K) {
  __shared__ bf16_t As[128 * 32];
  __shared__ bf16_t Bs[128 * 32];
  const int t = threadIdx.x;
  const int lane = t & 63, wave = t >> 6;
  const int wr = wave >> 1, wc = wave & 1;
  const int qr = lane & 15, g = lane >> 4;
  const int bm = blockIdx.x, bn = blockIdx.y;

  f32x4 acc[4][4];
#pragma unroll
  for (int m = 0; m < 4; m++)
#pragma unroll
    for (int n = 0; n < 4; n++) acc[m][n] = (f32x4){0.f, 0.f, 0.f, 0.f};

  const bf16_t* Abase = A + (size_t)(bm * 128) * K;
  const bf16_t* Bbase = Bm + (size_t)(bn * 128) * K;
  const int srow = t >> 2;
  const int scol = (t & 3) * 8;

  for (int kk = 0; kk < K; kk += 32) {
    gload_lds16(Abase + (size_t)srow * K + kk + scol,        As + t * 8);
    gload_lds16(Abase + (size_t)(srow + 64) * K + kk + scol, As + 2048 + t * 8);
    gload_lds16(Bbase + (size_t)srow * K + kk + scol,        Bs + t * 8);
    gload_lds16(Bbase + (size_t)(srow + 64) * K + kk + scol, Bs + 2048 + t * 8);
    __syncthreads();
    bf16x8 a[4], b[4];
#pragma unroll
    for (int m = 0; m < 4; m++)
      a[m] = *(const bf16x8*)(As + (wr * 64 + m * 16 + qr) * 32 + g * 8);
#pragma unroll
    for (int n = 0; n < 4; n++)
      b[n] = *(const bf16x8*)(Bs + (wc * 64 + n * 16 + qr) * 32 + g * 8);
#pragma unroll
    for (int m = 0; m < 4; m++)
#pragma unroll
      for (int n = 0; n < 4; n++)
        acc[m][n] = __builtin_amdgcn_mfma_f32_16x16x32_bf16(a[m], b[n], acc[m][n], 0, 0, 0);
    __syncthreads();
  }

#pragma unroll
  for (int m = 0; m < 4; m++) {
    int row0 = bm * 128 + wr * 64 + m * 16 + g * 4;
#pragma unroll
    for (int n = 0; n < 4; n++) {
      int col = bn * 128 + wc * 64 + n * 16 + qr;
#pragma unroll
      for (int r = 0; r < 4; r++)
        C[(size_t)(row0 + r) * N + col] = (OutT)acc[m][n][r];
    }
  }
}

// ---------------- RoPE on q,k + q-scale; writes Q,K as [B][H][S][HD] bf16 ----------------
__global__ void rope_qk_kernel(const bf16_t* __restrict__ qkv, const int* __restrict__ pos,
                               bf16_t* __restrict__ Q, bf16_t* __restrict__ Ko) {
  int idx = blockIdx.x * blockDim.x + threadIdx.x;
  if (idx >= B_ * S_ * H_ * 32) return;
  int i = idx & 31;
  int h = (idx >> 5) & (H_ - 1);
  int bs = idx >> 9;
  const bf16_t* row = qkv + (size_t)bs * (3 * D_) + h * 192;
  float q1 = (float)row[i], q2 = (float)row[i + 32];
  float k1 = (float)row[64 + i], k2 = (float)row[96 + i];
  int p = pos[bs];
  float inv = exp2f(-(float)i * (13.287712379549449f / 32.0f));
  float ang = (float)p * inv;
  float sn, cs;
  sincosf(ang, &sn, &cs);
  float qo1 = (q1 * cs - q2 * sn) * 0.125f;
  float qo2 = (q2 * cs + q1 * sn) * 0.125f;
  float ko1 = k1 * cs - k2 * sn;
  float ko2 = k2 * cs + k1 * sn;
  int b = bs >> 11, s = bs & (S_ - 1);
  size_t o = ((size_t)(b * H_ + h) * S_ + s) * HD_ + i;
  Q[o] = (__bf16)qo1;  Q[o + 32] = (__bf16)qo2;
  Ko[o] = (__bf16)ko1; Ko[o + 32] = (__bf16)ko2;
}

// ---------------- V transpose: qkv v-slice -> Vt [B][H][HD][S] bf16 ----------------
__global__ __launch_bounds__(256) void v_transpose_kernel(const bf16_t* __restrict__ qkv,
                                                          bf16_t* __restrict__ Vt) {
  __shared__ bf16_t tile[64][72];
  int t = threadIdx.x;
  int s0 = blockIdx.x * 64;
  int h = blockIdx.y, b = blockIdx.z;
  int sl = t >> 4;
  int cb = (t & 15) * 4;
#pragma unroll
  for (int it = 0; it < 4; it++) {
    int s = sl + it * 16;
    const bf16_t* src = qkv + (size_t)(b * S_ + s0 + s) * (3 * D_) + h * 192 + 128 + cb;
    bf16x4 v = *(const bf16x4*)src;
    tile[cb + 0][s] = v[0]; tile[cb + 1][s] = v[1];
    tile[cb + 2][s] = v[2]; tile[cb + 3][s] = v[3];
  }
  __syncthreads();
#pragma unroll
  for (int it = 0; it < 4; it++) {
    int d = sl + it * 16;
    bf16x4 v;
    v[0] = tile[d][cb]; v[1] = tile[d][cb + 1]; v[2] = tile[d][cb + 2]; v[3] = tile[d][cb + 3];
    *(bf16x4*)(Vt + ((size_t)((b * H_ + h) * HD_ + d)) * S_ + s0 + cb) = v;
  }
}

// ---------------- flash attention, swapped 32x32 MFMA structure ----------------
// grid: (S/128, H, B) with bx REVERSED (heavy q-blocks dispatch first).
// 256 threads = 4 waves; wave wv owns q rows [q0+wv*32, +32).
// Swapped QK^T: S^T[k][q] = K·Q^T  -> lane owns column q = lane&31, 16 k-rows/reg.
// Swapped PV:   O^T[d][q] = V^T·P  -> same lane-q ownership; softmax fully per-lane.
__global__ __launch_bounds__(256) void attn_kernel(const bf16_t* __restrict__ Q,
                                                   const bf16_t* __restrict__ K,
                                                   const bf16_t* __restrict__ Vt,
                                                   const int* __restrict__ pos,
                                                   bf16_t* __restrict__ O) {
  __shared__ bf16_t Ks[64 * 64];   // [k][d] 16B-chunk XOR swizzled
  __shared__ bf16_t Vs[64 * 64];   // [d][s] 16B-chunk XOR swizzled

  const int t = threadIdx.x;
  const int lane = t & 63, wv = t >> 6;
  const int l31 = lane & 31, hi = lane >> 5;
  const int h = blockIdx.y, b = blockIdx.z;
  const int qblk = gridDim.x - 1 - blockIdx.x;   // reversed: longest blocks first
  const int q0 = qblk * 128;

  const size_t bh = (size_t)(b * H_ + h);
  const bf16_t* Qb = Q + bh * (S_ * HD_);
  const bf16_t* Kb = K + bh * (S_ * HD_);
  const bf16_t* Vb = Vt + bh * (HD_ * S_);

  // Q fragments (B-operand): lane holds row q = q0+wv*32+l31, d = c*16 + 8*hi + j
  const int qrow = q0 + wv * 32 + l31;
  bf16x8 qf[4];
#pragma unroll
  for (int c = 0; c < 4; c++)
    qf[c] = *(const bf16x8*)(Qb + (size_t)qrow * HD_ + c * 16 + hi * 8);

  const int prow = pos[b * S_ + qrow];
  int wmin = prow;
#pragma unroll
  for (int off = 1; off < 32; off <<= 1) wmin = min(wmin, __shfl_xor(wmin, off));

  // block-wide max position (identical in all waves; each reads all 128 rows)
  int mp = max(pos[b * S_ + q0 + lane], pos[b * S_ + q0 + 64 + lane]);
#pragma unroll
  for (int off = 1; off < 64; off <<= 1) mp = max(mp, __shfl_xor(mp, off));
  const int ntiles = min(S_ / KVBLK, (mp >> 6) + 1);

  f32x16 oT[2];
#pragma unroll
  for (int dt = 0; dt < 2; dt++)
#pragma unroll
    for (int r = 0; r < 16; r++) oT[dt][r] = 0.f;
  float m_run = NINF, l_run = 0.f;

  for (int kt = 0; kt < ntiles; ++kt) {
    const int k0 = kt * KVBLK;
    __syncthreads();
    {
      int e0 = t, r0 = e0 >> 3, c0 = e0 & 7;
      int e1 = t + 256, r1 = e1 >> 3, c1 = e1 & 7;
      gload_lds16(Kb + (size_t)(k0 + r0) * HD_ + ((c0 ^ (r0 & 7)) * 8), Ks + e0 * 8);
      gload_lds16(Kb + (size_t)(k0 + r1) * HD_ + ((c1 ^ (r1 & 7)) * 8), Ks + e1 * 8);
      gload_lds16(Vb + (size_t)r0 * S_ + k0 + ((c0 ^ (r0 & 7)) * 8), Vs + e0 * 8);
      gload_lds16(Vb + (size_t)r1 * S_ + k0 + ((c1 ^ (r1 & 7)) * 8), Vs + e1 * 8);
    }
    __syncthreads();

    // QK^T swapped: s0 = K[k0..k0+31] x Q^T, s1 = K[k0+32..k0+63] x Q^T
    f32x16 s0, s1;
#pragma unroll
    for (int r = 0; r < 16; r++) { s0[r] = 0.f; s1[r] = 0.f; }
#pragma unroll
    for (int c = 0; c < 4; c++) {
      const int c2 = c * 2 + hi;
      const int kr0 = l31;
      const int kr1 = 32 + l31;
      bf16x8 kf0 = *(const bf16x8*)(Ks + kr0 * 64 + ((c2 ^ (kr0 & 7)) * 8));
      bf16x8 kf1 = *(const bf16x8*)(Ks + kr1 * 64 + ((c2 ^ (kr1 & 7)) * 8));
      s0 = __builtin_amdgcn_mfma_f32_32x32x16_bf16(kf0, qf[c], s0, 0, 0, 0);
      s1 = __builtin_amdgcn_mfma_f32_32x32x16_bf16(kf1, qf[c], s1, 0, 0, 0);
    }

    // mask (skip when tile fully visible for this wave)
    float p0[16], p1[16];
    if (k0 + 63 > wmin) {
#pragma unroll
      for (int r = 0; r < 16; r++) {
        int koff = (r & 3) + 8 * (r >> 2) + 4 * hi;
        p0[r] = (k0 + koff <= prow) ? s0[r] : NINF;
        p1[r] = (k0 + 32 + koff <= prow) ? s1[r] : NINF;
      }
    } else {
#pragma unroll
      for (int r = 0; r < 16; r++) { p0[r] = s0[r]; p1[r] = s1[r]; }
    }

    // per-lane online softmax for column q = l31
    float tm = NINF;
#pragma unroll
    for (int r = 0; r < 16; r++) tm = fmaxf(tm, fmaxf(p0[r], p1[r]));
    tm = fmaxf(tm, __shfl_xor(tm, 32));
    float mn = fmaxf(fmaxf(m_run, tm), -1e30f);
    float scale = exp2f((m_run - mn) * L2E);
    float mnl = mn * L2E;
    float rs = 0.f;
#pragma unroll
    for (int r = 0; r < 16; r++) {
      p0[r] = exp2f(p0[r] * L2E - mnl);
      p1[r] = exp2f(p1[r] * L2E - mnl);
      rs += p0[r] + p1[r];
    }
    rs += __shfl_xor(rs, 32);
    l_run = l_run * scale + rs;
    m_run = mn;
#pragma unroll
    for (int dt = 0; dt < 2; dt++)
#pragma unroll
      for (int r = 0; r < 16; r++) oT[dt][r] *= scale;

    // PV swapped: oT[dt] += V^T(32d x 16k) x P(16k x 32q), kc = k-chunk
#pragma unroll
    for (int kc = 0; kc < 4; kc++) {
      const float* P = (kc < 2) ? p0 : p1;
      const int rb = (kc & 1) * 8;
      uint32_t xa0 = packbf(P[rb + 0], P[rb + 1]);
      uint32_t xa1 = packbf(P[rb + 2], P[rb + 3]);
      uint32_t xb0 = packbf(P[rb + 4], P[rb + 5]);
      uint32_t xb1 = packbf(P[rb + 6], P[rb + 7]);
      uint32_t sa0 = (uint32_t)__shfl_xor((int)xa0, 32);
      uint32_t sa1 = (uint32_t)__shfl_xor((int)xa1, 32);
      uint32_t sb0 = (uint32_t)__shfl_xor((int)xb0, 32);
      uint32_t sb1 = (uint32_t)__shfl_xor((int)xb1, 32);
      union { uint32_t u[4]; bf16x8 v; } pf;
      pf.u[0] = hi ? sb0 : xa0;
      pf.u[1] = hi ? sb1 : xa1;
      pf.u[2] = hi ? xb0 : sa0;
      pf.u[3] = hi ? xb1 : sa1;
#pragma unroll
      for (int dt = 0; dt < 2; dt++) {
        const int vr = dt * 32 + l31;
        const int c2 = kc * 2 + hi;
        bf16x8 vf = *(const bf16x8*)(Vs + vr * 64 + ((c2 ^ (vr & 7)) * 8));
        oT[dt] = __builtin_amdgcn_mfma_f32_32x32x16_bf16(vf, pf.v, oT[dt], 0, 0, 0);
      }
    }
  }

  // epilogue: O^T (regs) -> LDS transpose -> coalesced global stores
  __syncthreads();  // all waves done reading Ks/Vs
  const float rl = (l_run > 0.f) ? 1.0f / l_run : 0.f;
  bf16_t* Ot = (wv < 2) ? (Ks + wv * 2048) : (Vs + (wv - 2) * 2048);  // [32 q][64 d] swizzled
#pragma unroll
  for (int dt = 0; dt < 2; dt++)
#pragma unroll
    for (int r = 0; r < 16; r++) {
      int chunk = dt * 4 + (r >> 2);
      int el = (r & 3) + 4 * hi;
      Ot[l31 * 64 + ((chunk ^ (l31 & 7)) * 8) + el] = (__bf16)(oT[dt][r] * rl);
    }
  __syncthreads();
#pragma unroll
  for (int it = 0; it < 4; it++) {
    int qr2 = (lane >> 3) + it * 8;
    int cc = lane & 7;
    bf16x8 v = *(const bf16x8*)(Ot + qr2 * 64 + ((cc ^ (qr2 & 7)) * 8));
    *(bf16x8*)(&O[(size_t)(b * S_ + q0 + wv * 32 + qr2) * D_ + h * 64 + cc * 8]) = v;
  }
}

extern "C" void kernel_launch(void* const* d_in, const int* in_sizes, int n_in,
                              void* d_out, int out_size, void* d_ws, size_t ws_size,
                              hipStream_t stream) {
  const float* inputs = (const float*)d_in[0];
  const int* positions = (const int*)d_in[1];
  const float* W_in = (const float*)d_in[2];
  const float* W_out = (const float*)d_in[3];
  float* out = (float*)d_out;

  bf16_t* X_bf = (bf16_t*)d_ws;
  bf16_t* Win_bf = X_bf + (size_t)4096 * 1024;
  bf16_t* Wout_bf = Win_bf + (size_t)3072 * 1024;
  bf16_t* qkv_bf = Wout_bf + (size_t)1024 * 1024;
  bf16_t* Qb = qkv_bf + (size_t)4096 * 3072;
  bf16_t* Kb = Qb + (size_t)B_ * H_ * S_ * HD_;
  bf16_t* Vtb = Kb + (size_t)B_ * H_ * S_ * HD_;
  bf16_t* Ob = Vtb + (size_t)B_ * H_ * S_ * HD_;

  cast_bf16_kernel<<<dim3(2048), dim3(256), 0, stream>>>(inputs, X_bf, (4096 * 1024) / 4);
  cast_bf16_kernel<<<dim3(2048), dim3(256), 0, stream>>>(W_in, Win_bf, (3072 * 1024) / 4);
  cast_bf16_kernel<<<dim3(1024), dim3(256), 0, stream>>>(W_out, Wout_bf, (1024 * 1024) / 4);

  gemm_bt<bf16_t><<<dim3(32, 24), dim3(256), 0, stream>>>(X_bf, Win_bf, qkv_bf, 4096, 3072, 1024);

  rope_qk_kernel<<<dim3((B_ * S_ * H_ * 32) / 256), dim3(256), 0, stream>>>(qkv_bf, positions, Qb, Kb);
  v_transpose_kernel<<<dim3(S_ / 64, H_, B_), dim3(256), 0, stream>>>(qkv_bf, Vtb);

  attn_kernel<<<dim3(S_ / 128, H_, B_), dim3(256), 0, stream>>>(Qb, Kb, Vtb, positions, Ob);

  gemm_bt<float><<<dim3(32, 8), dim3(256), 0, stream>>>(Ob, Wout_bf, out, 4096, 1024, 1024);
}